// Round 5
// baseline (223.054 us; speedup 1.0000x reference)
//
#include <hip/hip_runtime.h>

// SimpleRNN fused kernel for MI355X (gfx950).  B=32768, T=28, I=28, H=128, C=10.
//
// R12: barrier-free, LDS-free, recurrent state entirely in registers.
// Each wave owns 16 batches and all 128 h for the whole T=28 scan.
//   - W resident as 32 bf16 A-frags (128 VGPRs); U as 8 A-frags (32 VGPRs)
//     with Ub+Wb FOLDED into U columns k=28 (bias hi) and k=29 (bias lo
//     residual), and x[k=28]=x[k=29]=1.0 -> bias enters via the U MFMA at
//     ~f32 precision, no separate bias regs, no C-operand needed.
//   - State S kept as MFMA B-frags: scur[kt][p] u32 = bf16pair
//     (S[b=l][32kt+8q+2p], S[b=l][+1]), lane=(q,l)=(lane>>4,lane&15).
//   - D->B layout transpose done IN-REGISTER with ds_bpermute (no LDS
//     storage, no barrier): value pair at rows H=(32kt+8q_n+2p) comes from
//     lane q_p=(2q_n+(p>>1))&3, slot pk[2kt+(q_n>>1)][p&1].  Per word:
//     2 bpermute (vsrc pk[2kt], pk[2kt+1]) + select on lane>=32.
//     Verified by hand-trace: H=78 -> src lane(3,l) pk[0][1] -> dest
//     lane(1,l) word[2][3] via addrB; H=0,60,78 cases all check.
//   - x streamed from global, 1-step register prefetch (R8/R11-proven
//     addressing); q=3's upper half is the constant {1,1,0,0} bias carrier.
//   - Epilogue: out^T = Vw*S^T as ONE 16x16 MFMA chain (Vw rows as A-frags,
//     scur as B), Vb as initial acc; scatter-store c<10.
//   - ZERO __syncthreads / s_barrier; waves fully independent.  2048 waves
//     = 2/SIMD, one residency round.
// Why: R7/R10/R11 all pin at VALUBusy~53%, wall/step ~2x issue, occupancy
// ~36% regardless of LDS/VGPR headroom -> per-step barrier+chain bound.
// tanh VALU floor ~18us chip-wide; this removes everything else.
// VGPR ~240 est. (R8 precedent: 236 clean at plain launch_bounds(256)).
//
// MFMA 16x16x32 bf16 layouts (m89/m91):
//   A[m=lane&15][k=(lane>>4)*8+j]  B[k=(lane>>4)*8+j][n=lane&15]
//   D[(lane>>4)*4+r][lane&15]

#define T_STEPS 28

typedef __attribute__((ext_vector_type(4))) float f32x4;
typedef __attribute__((ext_vector_type(8))) short short8;

#define MFMA16 __builtin_amdgcn_mfma_f32_16x16x32_bf16

__device__ __forceinline__ unsigned pack2(float lo, float hi) {
#if __has_builtin(__builtin_amdgcn_cvt_pk_bf16_f32)
  auto p = __builtin_amdgcn_cvt_pk_bf16_f32(lo, hi);   // RNE pack, 1 inst
  return __builtin_bit_cast(unsigned, p);
#else
  unsigned a = __builtin_bit_cast(unsigned, lo);
  a += 0x7FFFu + ((a >> 16) & 1u);
  unsigned b = __builtin_bit_cast(unsigned, hi);
  b += 0x7FFFu + ((b >> 16) & 1u);
  return (a >> 16) | (b & 0xFFFF0000u);
#endif
}

__device__ __forceinline__ float bf2f(unsigned short s) {
  return __builtin_bit_cast(float, (unsigned)s << 16);
}

__device__ __forceinline__ short8 to_frag(f32x4 a, f32x4 b) {
  union { unsigned u[4]; short8 v; } r;
  r.u[0] = pack2(a[0], a[1]);
  r.u[1] = pack2(a[2], a[3]);
  r.u[2] = pack2(b[0], b[1]);
  r.u[3] = pack2(b[2], b[3]);
  return r.v;
}

__device__ __forceinline__ short8 frag_of(const unsigned* s4) {
  union { unsigned u[4]; short8 v; } r;
  r.u[0] = s4[0]; r.u[1] = s4[1]; r.u[2] = s4[2]; r.u[3] = s4[3];
  return r.v;
}

// Pade(5,4) tanh, scalar fp32 (best measured, R4): max err ~1.2e-3, den>=945.
__device__ __forceinline__ f32x4 tanh4(f32x4 z) {
  f32x4 x2 = z * z;
  f32x4 p = 945.0f + x2 * (105.0f + x2);
  f32x4 q = 945.0f + x2 * (420.0f + 15.0f * x2);
  f32x4 num = z * p;
  f32x4 r;
#pragma unroll
  for (int i = 0; i < 4; ++i) r[i] = __builtin_amdgcn_rcpf(q[i]);
  f32x4 t = num * r;
#pragma unroll
  for (int i = 0; i < 4; ++i) t[i] = __builtin_amdgcn_fmed3f(t[i], -1.0f, 1.0f);
  return t;
}

__global__ __launch_bounds__(256) void rnn_fused(
    const float* __restrict__ x,  const float* __restrict__ Uw,
    const float* __restrict__ Ub, const float* __restrict__ Ww,
    const float* __restrict__ Wb, const float* __restrict__ Vw,
    const float* __restrict__ Vb, float* __restrict__ out) {
  const int tid  = threadIdx.x;
  const int w    = tid >> 6;
  const int lane = tid & 63;
  const int l    = lane & 15;
  const int q    = lane >> 4;                  // 0..3
  const int bw   = (blockIdx.x * 4 + w) * 16;  // this wave's batch base
  const bool hi32 = lane >= 32;                // q_n >= 2 selector

  const f32x4 zero4 = {0.f, 0.f, 0.f, 0.f};

  // bpermute source-lane addresses (bytes).  Dest lane (q,l), word p:
  //   src lane = ((2q + (p>>1)) & 3)*16 + l
  const int addrA = ((((2 * q) & 3) << 4) + l) << 2;      // p>>1 == 0
  const int addrB = ((((2 * q + 1) & 3) << 4) + l) << 2;  // p>>1 == 1

  // ---- x streaming: batch b = bw+l, i-range q*8..q*8+7 (k>=28 = bias/0) ----
  const float* xp = x + (size_t)(bw + l) * 784 + q * 8;
  f32x4 xa = *(const f32x4*)xp;                // i = q*8..+3 (always valid)
  f32x4 xb = {1.f, 1.f, 0.f, 0.f};             // q==3: k=28,29 carry 1.0 (bias)
  if (q < 3) xb = *(const f32x4*)(xp + 4);

  // ---- persistent weight fragments (A-layout, rows h = mt*16 + l) ----
  short8 wfrag[8][4];   // [mt][kt]
  short8 ufrag[8];      // [mt]; k=28 -> bf16(bias), k=29 -> bf16(bias residual)
#pragma unroll
  for (int mt = 0; mt < 8; ++mt) {
    const int h = mt * 16 + l;
    const float* wp = Ww + h * 128 + q * 8;
#pragma unroll
    for (int kt = 0; kt < 4; ++kt)
      wfrag[mt][kt] = to_frag(*(const f32x4*)(wp + kt * 32),
                              *(const f32x4*)(wp + kt * 32 + 4));
    const float* up = Uw + h * 28 + q * 8;
    f32x4 u0 = *(const f32x4*)up;
    f32x4 u1 = zero4;
    if (q < 3) {
      u1 = *(const f32x4*)(up + 4);
    } else {
      float b  = Ub[h] + Wb[h];
      float bh = bf2f((unsigned short)(pack2(b, 0.f) & 0xFFFFu));
      u1[0] = b;                       // rounds to bf16(b) = bh in to_frag
      u1[1] = b - bh;                  // residual, rounds to bf16
    }
    ufrag[mt] = to_frag(u0, u1);
  }

  unsigned scur[4][4];   // state as B-frag words: scur[kt][p]

  // ---- t = 0 (S=0: U-projection + folded bias only) ----
  {
    short8 xf = to_frag(xa, xb);
    xa = *(const f32x4*)(xp + 28);             // prefetch t=1
    if (q < 3) xb = *(const f32x4*)(xp + 32);
#pragma unroll
    for (int g = 0; g < 2; ++g) {
      unsigned pk[4][2];                       // [i][s]: rows 16mt+4q+2s,+1
#pragma unroll
      for (int i = 0; i < 4; ++i) {
        f32x4 a  = MFMA16(ufrag[g * 4 + i], xf, zero4, 0, 0, 0);
        f32x4 th = tanh4(a);
        pk[i][0] = pack2(th[0], th[1]);
        pk[i][1] = pack2(th[2], th[3]);
      }
#pragma unroll
      for (int d = 0; d < 2; ++d)
#pragma unroll
        for (int p = 0; p < 4; ++p) {
          const int ad = (p >> 1) ? addrB : addrA;
          int r0 = __builtin_amdgcn_ds_bpermute(ad, (int)pk[2 * d][p & 1]);
          int r1 = __builtin_amdgcn_ds_bpermute(ad, (int)pk[2 * d + 1][p & 1]);
          scur[2 * g + d][p] = (unsigned)(hi32 ? r1 : r0);
        }
    }
  }

  // ---- t = 1 .. 27 : barrier-free, all-register recurrence ----
#pragma unroll 1
  for (int t = 1; t < T_STEPS; ++t) {
    short8 xf = to_frag(xa, xb);
    if (t < T_STEPS - 1) {                     // prefetch t+1
      const float* xn = xp + (t + 1) * 28;
      xa = *(const f32x4*)xn;
      if (q < 3) xb = *(const f32x4*)(xn + 4);
    }

    short8 sfr[4];                             // snapshot (MFMAs read this;
#pragma unroll                                 //  bperms overwrite scur)
    for (int kt = 0; kt < 4; ++kt) sfr[kt] = frag_of(scur[kt]);

#pragma unroll
    for (int g = 0; g < 2; ++g) {
      unsigned pk[4][2];
#pragma unroll
      for (int i = 0; i < 4; ++i) {
        const int mt = g * 4 + i;
        f32x4 a = MFMA16(wfrag[mt][0], sfr[0], zero4, 0, 0, 0);
#pragma unroll
        for (int kt = 1; kt < 4; ++kt)
          a = MFMA16(wfrag[mt][kt], sfr[kt], a, 0, 0, 0);
        a = MFMA16(ufrag[mt], xf, a, 0, 0, 0); // + U x (+ folded bias)
        f32x4 th = tanh4(a);
        pk[i][0] = pack2(th[0], th[1]);
        pk[i][1] = pack2(th[2], th[3]);
      }
#pragma unroll
      for (int d = 0; d < 2; ++d)
#pragma unroll
        for (int p = 0; p < 4; ++p) {
          const int ad = (p >> 1) ? addrB : addrA;
          int r0 = __builtin_amdgcn_ds_bpermute(ad, (int)pk[2 * d][p & 1]);
          int r1 = __builtin_amdgcn_ds_bpermute(ad, (int)pk[2 * d + 1][p & 1]);
          scur[2 * g + d][p] = (unsigned)(hi32 ? r1 : r0);
        }
    }
  }

  // ---- epilogue: out^T[c][b] = Vw * S^T + Vb, one 16x16 MFMA chain ----
  // A-frag rows m = c = l (zero for l>=10); B = scur; D rows c = q*4+r.
  {
    short8 vfrag[4];
    const float* vp = Vw + l * 128 + q * 8;
#pragma unroll
    for (int kt = 0; kt < 4; ++kt) {
      f32x4 v0 = zero4, v1 = zero4;
      if (l < 10) {
        v0 = *(const f32x4*)(vp + kt * 32);
        v1 = *(const f32x4*)(vp + kt * 32 + 4);
      }
      vfrag[kt] = to_frag(v0, v1);
    }
    f32x4 o;
#pragma unroll
    for (int r = 0; r < 4; ++r) {
      const int c = q * 4 + r;
      o[r] = (c < 10) ? Vb[c] : 0.f;
    }
#pragma unroll
    for (int kt = 0; kt < 4; ++kt)
      o = MFMA16(vfrag[kt], frag_of(scur[kt]), o, 0, 0, 0);
#pragma unroll
    for (int r = 0; r < 4; ++r) {
      const int c = q * 4 + r;
      if (c < 10) out[(size_t)(bw + l) * 10 + c] = o[r];
    }
  }
}

extern "C" void kernel_launch(void* const* d_in, const int* in_sizes, int n_in,
                              void* d_out, int out_size, void* d_ws, size_t ws_size,
                              hipStream_t stream) {
  const float* x  = (const float*)d_in[0];
  const float* Uw = (const float*)d_in[1];
  const float* Ub = (const float*)d_in[2];
  const float* Ww = (const float*)d_in[3];
  const float* Wb = (const float*)d_in[4];
  const float* Vw = (const float*)d_in[5];
  const float* Vb = (const float*)d_in[6];
  rnn_fused<<<512, 256, 0, stream>>>(x, Uw, Ub, Ww, Wb, Vw, Vb, (float*)d_out);
}

// Round 6
// 218.807 us; speedup vs baseline: 1.0194x; 1.0194x over previous
//
#include <hip/hip_runtime.h>

// SimpleRNN fused kernel for MI355X (gfx950).  B=32768, T=28, I=28, H=128, C=10.
//
// R13 = R7's exact step structure (best measured: 91 us) with the x staging
// cut to 1/3 so residency doubles.
//   R7-proven, kept verbatim:
//     - 4 waves/block, 16 batches/block; wave w owns h rows [32w, 32w+32)
//     - Sbuf[2][16*132] bf16 double-buffer (stride 132, measured conflict-ok)
//     - pure-LDS inner loop (NO in-loop global x) -> __syncthreads' vmcnt(0)
//       drain is free (this is what R11 gave up; it cost +15 us)
//     - scalar Pade(5,4) tanh (best measured), bias-as-MFMA-C, 10 MFMA/step
//     - __launch_bounds__(256,4): measured VGPR 52-64, zero spills
//   Changed:
//     - Xbuf stages 10 timesteps (16 x 324 u16 = 10.4 KB) instead of all 28
//       (28.8 KB); two mid-loop restages (t=10..19, t=20..27) of 7 coalesced
//       f32x4 loads/thread each + 1 extra barrier apiece.
//     - LDS 37.2 -> 18.8 KB  =>  8 blocks/CU = 32 waves/CU (100% nominal),
//       grid 2048 = exactly one residency round, no tail.
//       (R7 was LDS-capped at 4 blocks; R12 proved wave count > per-wave ILP;
//       cross-round invariant: VALU busy ~49 us both layouts -> wall =
//       busy/utilization -> raise utilization via residency.)
//     - X_STRIDE=324: row stride 648 B == 8 mod 128 -> same bank-residue
//       family as R7's measured pattern (900 u16 = 1800 B == 8 mod 128).
//
// MFMA 16x16x32 bf16 layouts (m89/m91):
//   A[m=lane&15][k=(lane>>4)*8+j]  B[k=(lane>>4)*8+j][n=lane&15]
//   D[(lane>>4)*4+r][lane&15]

#define T_STEPS 28
#define S_STRIDE 132
#define X_STRIDE 324        // 10*32 + 4 pad

typedef __attribute__((ext_vector_type(4))) float f32x4;
typedef __attribute__((ext_vector_type(8))) short short8;

#define MFMA16 __builtin_amdgcn_mfma_f32_16x16x32_bf16

__device__ __forceinline__ unsigned pack2(float lo, float hi) {
#if __has_builtin(__builtin_amdgcn_cvt_pk_bf16_f32)
  auto p = __builtin_amdgcn_cvt_pk_bf16_f32(lo, hi);   // RNE pack, 1 inst
  return __builtin_bit_cast(unsigned, p);
#else
  unsigned a = __builtin_bit_cast(unsigned, lo);
  a += 0x7FFFu + ((a >> 16) & 1u);
  unsigned b = __builtin_bit_cast(unsigned, hi);
  b += 0x7FFFu + ((b >> 16) & 1u);
  return (a >> 16) | (b & 0xFFFF0000u);
#endif
}

__device__ __forceinline__ short8 to_frag(f32x4 a, f32x4 b) {
  union { unsigned u[4]; short8 v; } r;
  r.u[0] = pack2(a[0], a[1]);
  r.u[1] = pack2(a[2], a[3]);
  r.u[2] = pack2(b[0], b[1]);
  r.u[3] = pack2(b[2], b[3]);
  return r.v;
}

__device__ __forceinline__ short8 load_frag64(const unsigned short* sp, int off) {
  // two b64 reads; measured conflict-free at the stride-132 pattern (R1/R3/R5/R10)
  union { uint2 d[2]; short8 v; } r;
  r.d[0] = *(const uint2*)(sp + off);
  r.d[1] = *(const uint2*)(sp + off + 4);
  return r.v;
}

// Pade(5,4) tanh, scalar fp32 (best measured, R4): max err ~1.2e-3, den>=945.
__device__ __forceinline__ f32x4 tanh4(f32x4 z) {
  f32x4 x2 = z * z;
  f32x4 p = 945.0f + x2 * (105.0f + x2);
  f32x4 q = 945.0f + x2 * (420.0f + 15.0f * x2);
  f32x4 num = z * p;
  f32x4 r;
#pragma unroll
  for (int i = 0; i < 4; ++i) r[i] = __builtin_amdgcn_rcpf(q[i]);
  f32x4 t = num * r;
#pragma unroll
  for (int i = 0; i < 4; ++i) t[i] = __builtin_amdgcn_fmed3f(t[i], -1.0f, 1.0f);
  return t;
}

// Stage NT timesteps [t0, t0+NT) of this block's 16 x-rows into Xbuf (bf16,
// k-padded to 32).  Slot s (f32x4): row = s/(NT*7), tt = (s%(NT*7))/7,
// j = s%7.  Global f32x4 at row*784 + (t0+tt)*28 + j*4 (16B-aligned: 112 and
// 3136 are multiples of 16).  Loads batched before stores (latency).
template <int NT>
__device__ __forceinline__ void stage_chunk(const float* __restrict__ xblk,
                                            unsigned short* __restrict__ Xb,
                                            int tid, int t0) {
  constexpr int SLOTS = 16 * NT * 7;
  constexpr int ITERS = (SLOTS + 255) / 256;
  f32x4 xr[ITERS];
#pragma unroll
  for (int k = 0; k < ITERS; ++k) {
    const int s = tid + 256 * k;
    if (s < SLOTS) {
      const int row = s / (NT * 7), g = s - row * (NT * 7);
      const int tt = g / 7, j = g - tt * 7;
      xr[k] = *(const f32x4*)(xblk + row * 784 + (t0 + tt) * 28 + j * 4);
    }
  }
#pragma unroll
  for (int k = 0; k < ITERS; ++k) {
    const int s = tid + 256 * k;
    if (s < SLOTS) {
      const int row = s / (NT * 7), g = s - row * (NT * 7);
      const int tt = g / 7, j = g - tt * 7;
      uint2 d; d.x = pack2(xr[k][0], xr[k][1]); d.y = pack2(xr[k][2], xr[k][3]);
      *(uint2*)(Xb + row * X_STRIDE + tt * 32 + j * 4) = d;
      if (j == 0) {                       // zero k=28..31 once per (row,tt)
        uint2 zz; zz.x = 0u; zz.y = 0u;
        *(uint2*)(Xb + row * X_STRIDE + tt * 32 + 28) = zz;
      }
    }
  }
}

__global__ __launch_bounds__(256, 4) void rnn_fused(
    const float* __restrict__ x,  const float* __restrict__ Uw,
    const float* __restrict__ Ub, const float* __restrict__ Ww,
    const float* __restrict__ Wb, const float* __restrict__ Vw,
    const float* __restrict__ Vb, float* __restrict__ out) {
  __shared__ __align__(16) unsigned short Sbuf[2][16 * S_STRIDE];  //  8448 B
  __shared__ __align__(16) unsigned short Xbuf[16 * X_STRIDE];     // 10368 B

  const int tid  = threadIdx.x;
  const int w    = tid >> 6;
  const int lane = tid & 63;
  const int l15  = lane & 15;
  const int q    = lane >> 4;           // 0..3
  const int mrow = w * 32;              // h base for this wave (2 m-tiles)
  const int b0   = blockIdx.x * 16;

  const f32x4 zero4 = {0.f, 0.f, 0.f, 0.f};
  const float* xblk = x + (size_t)b0 * 784;

  // ---- prologue: stage chunk 0 (t = 0..9) ----
  stage_chunk<10>(xblk, Xbuf, tid, 0);

  // ---- persistent weight fragments (after staging regs die) ----
  short8 wfrag[2][4];   // [mt][kt]
  short8 ufrag[2];      // [mt], K=32 padded (k>=28 zeroed)
  f32x4  bias[2];       // Ub[h]+Wb[h] at D rows h = mrow + mt*16 + q*4 + r
#pragma unroll
  for (int mt = 0; mt < 2; ++mt) {
    const int h = mrow + mt * 16 + l15;
    const float* wp = Ww + h * 128 + q * 8;
#pragma unroll
    for (int kt = 0; kt < 4; ++kt) {
      wfrag[mt][kt] = to_frag(*(const f32x4*)wp, *(const f32x4*)(wp + 4));
      wp += 32;
    }
    const float* up = Uw + h * 28 + q * 8;
    f32x4 u0 = *(const f32x4*)up;
    f32x4 u1 = zero4;
    if (q < 3) u1 = *(const f32x4*)(up + 4);
    ufrag[mt] = to_frag(u0, u1);
    const int hb = mrow + mt * 16 + q * 4;
    bias[mt] = *(const f32x4*)(Wb + hb) + *(const f32x4*)(Ub + hb);
  }
  __syncthreads();   // Xbuf chunk 0 visible

  const int ro = l15 * S_STRIDE;            // S row base (batch = l15)
  const int xo = l15 * X_STRIDE + q * 8;    // x frag base
  f32x4 acc[2];

  // one recurrence step: reads Xbuf slot tt and Sbuf[t&1], writes
  // Sbuf[(t+1)&1], ends with the block barrier.  (R7 body verbatim.)
  auto step = [&](int t, int tt) {
    short8 xf = load_frag64(&Xbuf[0], xo + tt * 32);
    const unsigned short* sp = &Sbuf[t & 1][0] + ro + q * 8;

    short8 sA = load_frag64(sp, 0);         // kt=0 with bias as C-operand
#pragma unroll
    for (int mt = 0; mt < 2; ++mt)
      acc[mt] = MFMA16(wfrag[mt][0], sA, bias[mt], 0, 0, 0);
#pragma unroll
    for (int kt = 1; kt < 4; ++kt) {
      sA = load_frag64(sp, kt * 32);
#pragma unroll
      for (int mt = 0; mt < 2; ++mt)
        acc[mt] = MFMA16(wfrag[mt][kt], sA, acc[mt], 0, 0, 0);
    }
#pragma unroll
    for (int mt = 0; mt < 2; ++mt)
      acc[mt] = MFMA16(ufrag[mt], xf, acc[mt], 0, 0, 0);

    unsigned short* wp = &Sbuf[(t + 1) & 1][0];
#pragma unroll
    for (int mt = 0; mt < 2; ++mt) {
      f32x4 th = tanh4(acc[mt]);
      uint2 dd; dd.x = pack2(th[0], th[1]); dd.y = pack2(th[2], th[3]);
      *(uint2*)(wp + ro + mrow + mt * 16 + q * 4) = dd;
    }
    __syncthreads();
  };

  // ---- t = 0 (S=0: projection only), write Sbuf[1] ----
  {
    short8 xf = load_frag64(&Xbuf[0], xo);
    unsigned short* wp = &Sbuf[1][0];
#pragma unroll
    for (int mt = 0; mt < 2; ++mt) {
      f32x4 d0 = MFMA16(ufrag[mt], xf, bias[mt], 0, 0, 0);
      f32x4 t0 = tanh4(d0);
      uint2 dd; dd.x = pack2(t0[0], t0[1]); dd.y = pack2(t0[2], t0[3]);
      *(uint2*)(wp + ro + mrow + mt * 16 + q * 4) = dd;
    }
  }
  __syncthreads();

  // ---- t = 1..9 on chunk 0 ----
#pragma unroll 1
  for (int t = 1; t < 10; ++t) step(t, t);

  // ---- restage chunk 1 (t = 10..19); chunk 0 fully consumed at t=9 ----
  stage_chunk<10>(xblk, Xbuf, tid, 10);
  __syncthreads();
#pragma unroll 1
  for (int t = 10; t < 20; ++t) step(t, t - 10);

  // ---- restage chunk 2 (t = 20..27) ----
  stage_chunk<8>(xblk, Xbuf, tid, 20);
  __syncthreads();
#pragma unroll 1
  for (int t = 20; t < T_STEPS; ++t) step(t, t - 20);

  // ---- epilogue: out[b][c] = sum_h S[b][h]*Vw[c][h] + Vb[c] ----
  // Final S in Sbuf[(27+1)&1] = Sbuf[0].  16 rows x 10 cols per block.
  {
    const int r  = tid >> 4;        // 0..15
    const int c0 = tid & 15;        // only c0<10 active
    if (c0 < 10) {
      const float* vp = Vw + c0 * 128;
      const unsigned short* srow = &Sbuf[0][0] + r * S_STRIDE;
      float a0 = Vb[c0];
#pragma unroll
      for (int h = 0; h < 128; h += 4) {
        uint2 d  = *(const uint2*)(srow + h);       // 4 bf16, 8B aligned
        f32x4 v4 = *(const f32x4*)(vp + h);
        a0 += __builtin_bit_cast(float, d.x << 16) * v4[0];
        a0 += __builtin_bit_cast(float, d.x & 0xFFFF0000u) * v4[1];
        a0 += __builtin_bit_cast(float, d.y << 16) * v4[2];
        a0 += __builtin_bit_cast(float, d.y & 0xFFFF0000u) * v4[3];
      }
      out[(size_t)(b0 + r) * 10 + c0] = a0;
    }
  }
}

extern "C" void kernel_launch(void* const* d_in, const int* in_sizes, int n_in,
                              void* d_out, int out_size, void* d_ws, size_t ws_size,
                              hipStream_t stream) {
  const float* x  = (const float*)d_in[0];
  const float* Uw = (const float*)d_in[1];
  const float* Ub = (const float*)d_in[2];
  const float* Ww = (const float*)d_in[3];
  const float* Wb = (const float*)d_in[4];
  const float* Vw = (const float*)d_in[5];
  const float* Vb = (const float*)d_in[6];
  rnn_fused<<<2048, 256, 0, stream>>>(x, Uw, Ub, Ww, Wb, Vw, Vb, (float*)d_out);
}